// Round 2
// baseline (520.466 us; speedup 1.0000x reference)
//
#include <hip/hip_runtime.h>
#include <hip/hip_bf16.h>

// ---------------- problem constants ----------------
#define HW    4096      // H*W
#define BB    8         // batch
#define TT    8         // time steps

// ws layout (in floats)
constexpr int OFF_WFRAG = 0;                   // 34 frags * 64 lanes * 16B = 8704 floats
constexpr int OFF_WTOUT = OFF_WFRAG + 8704;    // 4096 floats (Wt_out[c][o])
constexpr int OFF_WXB   = OFF_WTOUT + 4096;    // 256 float2 = 512 floats {w_x, bias}

// gate pre-scales folded into w_hh / w_x / bias at prep time:
//   i,f,o rows: * -log2(e)   -> sigmoid(x) = rcp(exp2(acc)+1)
//   g rows:     * 2*log2(e)  -> tanh(x) = (exp2(acc)-1)/(exp2(acc)+1)
constexpr float SI = -1.44269504088896340736f; // -log2(e)
constexpr float SG =  2.88539008177792681472f; // 2*log2(e)

typedef _Float16 halfx8 __attribute__((ext_vector_type(8)));
typedef float    floatx4 __attribute__((ext_vector_type(4)));
typedef float    floatx2 __attribute__((ext_vector_type(2)));

__device__ inline float fast_exp2(float x) {
#if __has_builtin(__builtin_amdgcn_exp2f)
    return __builtin_amdgcn_exp2f(x);
#else
    return __builtin_exp2f(x);
#endif
}
__device__ inline float fast_rcp(float x) {
#if __has_builtin(__builtin_amdgcn_rcpf)
    return __builtin_amdgcn_rcpf(x);
#else
    return 1.0f / x;
#endif
}
__device__ inline floatx2 exp2x2(floatx2 x) {
    floatx2 r; r.x = fast_exp2(x.x); r.y = fast_exp2(x.y); return r;
}
__device__ inline floatx2 rcpx2(floatx2 x) {
    floatx2 r; r.x = fast_rcp(x.x); r.y = fast_rcp(x.y); return r;
}

union pack8 { _Float16 h[8]; uint4 u; };

// ---------------- prep: repack weights into d_ws (12 blocks, wide) ----------------
// r9: 12 blocks; folds the activation pre-scales (SI/SG) into the f16
// B-fragments and the {w_x,bias} table so the t-loop exp2 args come straight
// out of the MFMA accumulators.
__global__ __launch_bounds__(256) void prep_kernel(
    const float* __restrict__ w_ih,  const float* __restrict__ w_hh,
    const float* __restrict__ b_ih,  const float* __restrict__ b_hh,
    const float* __restrict__ w_s,   const float* __restrict__ w_out,
    float* __restrict__ ws_f) {
    int tid = threadIdx.x;
    int bid = blockIdx.x;
    if (bid < 9) {
        // w_hh -> B-fragment-ordered f16 (pre-scaled). frag fi = nb*2+kc;
        // entry e = fi*64 + lane. lane l holds B[k=kc*32+(l>>4)*8+j][n=(l&15)]:
        // w_hh[gate=(l&15)+16*nb][hid=k] * scale(gate)
        int e = bid * 256 + tid;
        uint4* wf = (uint4*)(ws_f + OFF_WFRAG);
        if (e < 2048) {
            int l  = e & 63;
            int fi = e >> 6;
            int nb = fi >> 1, kc = fi & 1;
            int gate = (l & 15) + 16 * nb;
            int hid  = kc * 32 + (l >> 4) * 8;
            float sc = (gate >= 128 && gate < 192) ? SG : SI;
            const float* src = w_hh + gate * 64 + hid;
            pack8 p;
            #pragma unroll
            for (int j = 0; j < 8; ++j) p.h[j] = (_Float16)(src[j] * sc);
            wf[e] = p.u;
        } else if (e < 2176) {
            // s-projection fragments (frags 32,33): B[k][0]=w_s[k] (UNSCALED)
            int t2 = e - 2048;
            int l = t2 & 63, kc = t2 >> 6;
            pack8 p;
            #pragma unroll
            for (int j = 0; j < 8; ++j) p.h[j] = (_Float16)0.0f;
            if ((l & 15) == 0) {
                #pragma unroll
                for (int j = 0; j < 8; ++j)
                    p.h[j] = (_Float16)w_s[kc * 32 + (l >> 4) * 8 + j];
            }
            wf[e] = p.u;
        }
    } else if (bid == 9) {
        // {w_x, bias} pairs, pre-scaled per gate row
        floatx2* wxb = (floatx2*)(ws_f + OFF_WXB);
        float sc = (tid >= 128 && tid < 192) ? SG : SI;
        floatx2 v; v.x = w_ih[tid] * sc; v.y = (b_ih[tid] + b_hh[tid]) * sc;
        wxb[tid] = v;
    } else {
        // bid 10,11: transposed conv-out weights: Wt[c][o] = w_out[o][c]
        #pragma unroll
        for (int i = 0; i < 8; ++i) {
            int idx = (bid - 10) * 2048 + tid + 256 * i;
            int o = idx & 63, c = idx >> 6;
            ws_f[OFF_WTOUT + idx] = w_out[o * 64 + c];
        }
    }
}

// ---------------- fully fused conv_in + LSTM + conv_out ----------------
// Block = 512 threads = 8 waves = ONE 16-pixel tile x ALL 8 groups (wave wv
// handles group g=wv). All 64 s-channels of the tile stay block-resident in
// LDS -> no s_buf global round-trip.
// r9 activation rewrite: common-denominator LSTM cell; 5 exp2 + 2 rcp /elem.
// r10: B-fragments hoisted into REGISTERS before the t-loop (32 x halfx8 =
// 128 VGPR + 8 for s-frags). Previously every thread re-read all 512 B of
// frags from LDS every t (~17.8 MB/CU of ds_read_b128 ~= 87 us of LDS pipe)
// -- the dominant non-VALU cost + 32 lgkm stalls/t. Controlled hoist (named
// regs, loaded once) instead of r7's "let compiler cache" (which ballooned).
// The asm clobber STAYS so wxb/x/h LDS reads are not cached (r8 lesson:
// wxb-in-regs regressed). __launch_bounds__(512,4) states the LDS-imposed
// occupancy (2 blocks/CU = 4 waves/SIMD) so the allocator doesn't squeeze
// to 52 regs and spill the cached frags. Total VGPR ~200-256 << 512 budget.
// LDS = 79872 B <= 81920 -> 2 blocks/CU.
__global__ __launch_bounds__(512, 4) void lstm_kernel(
    const float* __restrict__ hin,    // (B, 64, HW) original input h
    const float* __restrict__ ws_f,   // tables
    float* __restrict__ out,          // (B, 64, HW) final output
    const float* __restrict__ w_in,   // (64, 64)
    const float* __restrict__ b_in,   // (64,)
    const float* __restrict__ b_s_p,  // (1,)
    const float* __restrict__ b_out) {// (64,)
    __shared__ uint4 wfrag_lds[2176];                  // 34816 B
    __shared__ floatx2 wxb_lds[256];                   // 2048 B
    __shared__ __align__(16) float x_lds[1024];        // 4096 B: [g][t][px16]
    __shared__ __align__(16) _Float16 h_lds[9216];     // 18432 B: 8 waves x 16 x 72
    __shared__ __align__(16) float stile[1024];        // 4096 B: [c64][px16]; aliases hin staging
    __shared__ __align__(16) float wt_lds[4096];       // 16384 B: w_in, then Wt_out

    int tid = threadIdx.x;
    int ptile = blockIdx.x & 255;         // 256 tiles of 16 px
    int b     = blockIdx.x >> 8;
    int p0 = ptile * 16;

    int lane = tid & 63;
    int wv   = tid >> 6;                  // 0..7 == group g
    int g    = wv;
    int s    = lane & 15;                 // seq-local == pixel-local
    int q    = lane >> 4;

    // stage weight fragments (shared by all 8 waves)
    const uint4* wfg = (const uint4*)(ws_f + OFF_WFRAG);
    #pragma unroll
    for (int i = 0; i < 5; ++i) {
        int e = tid + 512 * i;
        if (e < 2176) wfrag_lds[e] = wfg[e];
    }
    if (tid < 256) wxb_lds[tid] = ((const floatx2*)(ws_f + OFF_WXB))[tid];
    // stage w_in (identity copy, [o][c] row-major) into wt_lds
    #pragma unroll
    for (int i = 0; i < 2; ++i)
        ((floatx4*)wt_lds)[tid + 512 * i] = ((const floatx4*)w_in)[tid + 512 * i];
    // stage hin tile (64 ch x 16 px) into stile (aliased)
    if (tid < 256) {
        int cc = tid >> 2, f4 = tid & 3;
        ((floatx4*)stile)[tid] = *(const floatx4*)&hin[(b * 64 + cc) * HW + p0 + f4 * 4];
    }
    __syncthreads();

    // ---- conv_in (per wave, own group): x[g][t][px] = sum_c w_in[g8+t][c]*hin[c][px] + b_in
    {
        floatx2 xacc; xacc.x = b_in[g * 8 + q]; xacc.y = b_in[g * 8 + q + 4];
        #pragma unroll 8
        for (int cc = 0; cc < 64; ++cc) {
            float hv = stile[cc * 16 + s];
            floatx2 w;
            w.x = wt_lds[(g * 8 + q) * 64 + cc];
            w.y = wt_lds[(g * 8 + q + 4) * 64 + cc];
            floatx2 h2; h2.x = hv; h2.y = hv;
            xacc = xacc + w * h2;
        }
        x_lds[g * 128 + q * 16 + s]       = xacc.x;
        x_lds[g * 128 + (q + 4) * 16 + s] = xacc.y;
    }
    // zero h state (4608 u32)
    #pragma unroll
    for (int i = 0; i < 9; ++i)
        ((unsigned*)h_lds)[tid + 512 * i] = 0u;
    __syncthreads();   // hin/w_in reads + x/h writes complete

    // stage Wt_out ([c][o]) into wt_lds for the epilogue (read after next barrier)
    #pragma unroll
    for (int i = 0; i < 2; ++i)
        ((floatx4*)wt_lds)[tid + 512 * i] =
            ((const floatx4*)(ws_f + OFF_WTOUT))[tid + 512 * i];

    // ---- r10: hoist ALL B-fragments into registers (loaded ONCE).
    // 32 gate-frags (128 VGPR) + 2 s-proj frags (8 VGPR). These are SSA
    // register values: the asm clobber below does not invalidate them.
    halfx8 bf[16][2];
    #pragma unroll
    for (int nb = 0; nb < 16; ++nb) {
        bf[nb][0] = *(const halfx8*)&wfrag_lds[(nb * 2 + 0) * 64 + lane];
        bf[nb][1] = *(const halfx8*)&wfrag_lds[(nb * 2 + 1) * 64 + lane];
    }
    halfx8 sb0 = *(const halfx8*)&wfrag_lds[32 * 64 + lane];
    halfx8 sb1 = *(const halfx8*)&wfrag_lds[33 * 64 + lane];

    _Float16* hrow = h_lds + wv * 16 * 72;
    float bs = b_s_p[0];

    // c-state, stored PRE-SCALED by 2*log2(e)
    float c_st[4][4];
    #pragma unroll
    for (int hb = 0; hb < 4; ++hb)
        #pragma unroll
        for (int r = 0; r < 4; ++r) c_st[hb][r] = 0.0f;

    for (int t = 0; t < TT; ++t) {
        // Memory barrier: forbids caching LDS (wxb/x/h) in registers across
        // iterations (r8: wxb-in-regs regressed). Frag REGS above survive it.
        asm volatile("" ::: "memory");

        halfx8 a0 = *(const halfx8*)(hrow + s * 72 + q * 8);        // k = 0..31
        halfx8 a1 = *(const halfx8*)(hrow + s * 72 + q * 8 + 32);   // k = 32..63

        // s_{t-1} = h_t @ w_s via MFMA (col 0 only); lanes s==0 hold seq q*4+r
        if (t > 0) {
            floatx4 sa = {0.f, 0.f, 0.f, 0.f};
            sa = __builtin_amdgcn_mfma_f32_16x16x32_f16(a0, sb0, sa, 0, 0, 0);
            sa = __builtin_amdgcn_mfma_f32_16x16x32_f16(a1, sb1, sa, 0, 0, 0);
            if (s == 0) {
                floatx4 o4 = {sa[0] + bs, sa[1] + bs, sa[2] + bs, sa[3] + bs};
                *(floatx4*)&stile[(g * 8 + (t - 1)) * 16 + q * 4] = o4;
            }
        }

        floatx4 xv = *(const floatx4*)&x_lds[g * 128 + t * 16 + q * 4];
        floatx2 xlo; xlo.x = xv[0]; xlo.y = xv[1];
        floatx2 xhi; xhi.x = xv[2]; xhi.y = xv[3];

        #pragma unroll
        for (int hb = 0; hb < 4; ++hb) {
            floatx4 acc[4];
            #pragma unroll
            for (int gi = 0; gi < 4; ++gi) {
                int nb = hb + 4 * gi;
                floatx2 wb = wxb_lds[s + 16 * nb];
                floatx2 lo = xlo * wb.x + wb.y;     // x*w_x + bias as C init (pk_fma)
                floatx2 hi = xhi * wb.x + wb.y;
                floatx4 a = {lo.x, lo.y, hi.x, hi.y};
                a = __builtin_amdgcn_mfma_f32_16x16x32_f16(a0, bf[nb][0], a, 0, 0, 0);
                a = __builtin_amdgcn_mfma_f32_16x16x32_f16(a1, bf[nb][1], a, 0, 0, 0);
                acc[gi] = a;
            }
            int s16 = s + 16 * hb;
            _Float16* wp = hrow + (q * 4) * 72 + s16;
            #pragma unroll
            for (int p = 0; p < 2; ++p) {
                int r0 = 2 * p;
                // accs are pre-scaled: Ei=e^-i, Ef=e^-f, Eo=e^-o, Eg=e^{2g}
                floatx2 Ei; Ei.x = fast_exp2(acc[0][r0]); Ei.y = fast_exp2(acc[0][r0 + 1]);
                floatx2 Ef; Ef.x = fast_exp2(acc[1][r0]); Ef.y = fast_exp2(acc[1][r0 + 1]);
                floatx2 Eg; Eg.x = fast_exp2(acc[2][r0]); Eg.y = fast_exp2(acc[2][r0 + 1]);
                floatx2 Eo; Eo.x = fast_exp2(acc[3][r0]); Eo.y = fast_exp2(acc[3][r0 + 1]);
                floatx2 Bf  = Ef + 1.0f;
                floatx2 Pig = (Ei + 1.0f) * (Eg + 1.0f);
                floatx2 cp; cp.x = c_st[hb][r0]; cp.y = c_st[hb][r0 + 1];
                // cs' = f*cs + 2log2e * i*g  ==  [cs*Pig + SG*(Eg-1)*Bf] / (Bf*Pig)
                floatx2 num = cp * Pig + (Eg * SG - SG) * Bf;   // fma: SG*(Eg-1) exact
                floatx2 cs  = num * rcpx2(Bf * Pig);
                c_st[hb][r0] = cs.x; c_st[hb][r0 + 1] = cs.y;
                // h = o*tanh(c) = (Ec-1) / ((1+Eo)(1+Ec)),  Ec = exp2(cs) = e^{2c}
                floatx2 Ec  = exp2x2(cs);
                floatx2 hn  = (Ec - 1.0f) * rcpx2((Eo + 1.0f) * (Ec + 1.0f));
                wp[(r0 + 0) * 72] = (_Float16)hn.x;   // state for t+1
                wp[(r0 + 1) * 72] = (_Float16)hn.y;
            }
        }
    }
    // final s_7 from h_8
    {
        asm volatile("" ::: "memory");
        halfx8 a0 = *(const halfx8*)(hrow + s * 72 + q * 8);
        halfx8 a1 = *(const halfx8*)(hrow + s * 72 + q * 8 + 32);
        floatx4 sa = {0.f, 0.f, 0.f, 0.f};
        sa = __builtin_amdgcn_mfma_f32_16x16x32_f16(a0, sb0, sa, 0, 0, 0);
        sa = __builtin_amdgcn_mfma_f32_16x16x32_f16(a1, sb1, sa, 0, 0, 0);
        if (s == 0) {
            floatx4 o4 = {sa[0] + bs, sa[1] + bs, sa[2] + bs, sa[3] + bs};
            *(floatx4*)&stile[(g * 8 + 7) * 16 + q * 4] = o4;
        }
    }
    __syncthreads();   // stile (all 64 channels) + wt_lds (Wt_out) ready

    // ---- conv_out epilogue: out[b][o][p0+px] = sum_c Wt_out[c][o]*stile[c][px] + b_out[o]
    {
        int px = tid & 15;
        int oo = tid >> 4;                 // 0..31 -> outputs oo and oo+32
        floatx2 acc; acc.x = b_out[oo]; acc.y = b_out[oo + 32];
        #pragma unroll 8
        for (int c = 0; c < 64; ++c) {
            float sv = stile[c * 16 + px];
            floatx2 w;
            w.x = wt_lds[c * 64 + oo];
            w.y = wt_lds[c * 64 + oo + 32];
            floatx2 s2; s2.x = sv; s2.y = sv;
            acc = acc + w * s2;
        }
        out[(b * 64 + oo) * HW + p0 + px]      = acc.x;
        out[(b * 64 + oo + 32) * HW + p0 + px] = acc.y;
    }
}

extern "C" void kernel_launch(void* const* d_in, const int* in_sizes, int n_in,
                              void* d_out, int out_size, void* d_ws, size_t ws_size,
                              hipStream_t stream) {
    const float* h     = (const float*)d_in[0];
    const float* w_in  = (const float*)d_in[1];
    const float* b_in  = (const float*)d_in[2];
    const float* w_ih  = (const float*)d_in[3];
    const float* w_hh  = (const float*)d_in[4];
    const float* b_ih  = (const float*)d_in[5];
    const float* b_hh  = (const float*)d_in[6];
    const float* w_s   = (const float*)d_in[7];
    const float* b_s   = (const float*)d_in[8];
    const float* w_out = (const float*)d_in[9];
    const float* b_out = (const float*)d_in[10];
    float* out = (float*)d_out;
    float* ws  = (float*)d_ws;

    prep_kernel<<<12, 256, 0, stream>>>(w_ih, w_hh, b_ih, b_hh, w_s, w_out, ws);
    // fully fused conv_in + LSTM + conv_out: hin -> out. 2048 blocks x 512 threads.
    lstm_kernel<<<2048, 512, 0, stream>>>(h, ws, out, w_in, b_in, b_s, b_out);
}

// Round 3
// 481.488 us; speedup vs baseline: 1.0810x; 1.0810x over previous
//
#include <hip/hip_runtime.h>
#include <hip/hip_bf16.h>

// ---------------- problem constants ----------------
#define HW    4096      // H*W
#define BB    8         // batch
#define TT    8         // time steps

// ws layout (in floats)
constexpr int OFF_WFRAG = 0;                   // 34 frags * 64 lanes * 16B = 8704 floats
constexpr int OFF_WXB   = 12800;               // 256 float2 = 512 floats {w_x, bias}

// gate pre-scales folded into w_hh / w_x / bias at prep time:
//   i,f,o rows: * -log2(e)   -> sigmoid(x) = rcp(exp2(acc)+1)
//   g rows:     * 2*log2(e)  -> tanh(x) = (exp2(acc)-1)/(exp2(acc)+1)
constexpr float SI = -1.44269504088896340736f; // -log2(e)
constexpr float SG =  2.88539008177792681472f; // 2*log2(e)

typedef _Float16 halfx8 __attribute__((ext_vector_type(8)));
typedef _Float16 halfx4 __attribute__((ext_vector_type(4)));
typedef float    floatx4 __attribute__((ext_vector_type(4)));
typedef float    floatx2 __attribute__((ext_vector_type(2)));

__device__ inline float fast_exp2(float x) {
#if __has_builtin(__builtin_amdgcn_exp2f)
    return __builtin_amdgcn_exp2f(x);
#else
    return __builtin_exp2f(x);
#endif
}
__device__ inline float fast_rcp(float x) {
#if __has_builtin(__builtin_amdgcn_rcpf)
    return __builtin_amdgcn_rcpf(x);
#else
    return 1.0f / x;
#endif
}
__device__ inline floatx2 exp2x2(floatx2 x) {
    floatx2 r; r.x = fast_exp2(x.x); r.y = fast_exp2(x.y); return r;
}
__device__ inline floatx2 rcpx2(floatx2 x) {
    floatx2 r; r.x = fast_rcp(x.x); r.y = fast_rcp(x.y); return r;
}

union pack8 { _Float16 h[8]; uint4 u; };

// ---------------- prep: repack weights into d_ws (10 blocks) ----------------
// r9: folds activation pre-scales (SI/SG) into the f16 B-fragments and the
// {w_x,bias} table so t-loop exp2 args come straight out of the MFMA accs.
// r11: gate-column PERMUTATION — frag column sc of block nb=(hb+4gi) now holds
// orig gate row 64*gi + 4*sc + hb (was sc + 16*hb + 64*gi). Thread (s,hb)
// then produces hid = 4s+hb -> its 4 hb-values are CONTIGUOUS in h_lds ->
// one ds_write_b64 per row instead of 4 ds_write_b16. k-indexing (storage
// hid = orig hid), w_s frags and A-frag reads are unchanged by this.
__global__ __launch_bounds__(256) void prep_kernel(
    const float* __restrict__ w_ih,  const float* __restrict__ w_hh,
    const float* __restrict__ b_ih,  const float* __restrict__ b_hh,
    const float* __restrict__ w_s,   const float* __restrict__ w_out,
    float* __restrict__ ws_f) {
    int tid = threadIdx.x;
    int bid = blockIdx.x;
    if (bid < 9) {
        int e = bid * 256 + tid;
        uint4* wf = (uint4*)(ws_f + OFF_WFRAG);
        if (e < 2048) {
            int l  = e & 63;
            int fi = e >> 6;
            int nb = fi >> 1, kc = fi & 1;
            int hb = nb & 3, gi = nb >> 2;
            int gate = gi * 64 + 4 * (l & 15) + hb;   // r11 permuted column
            int hid  = kc * 32 + (l >> 4) * 8;
            float sc = (gi == 2) ? SG : SI;
            const float* src = w_hh + gate * 64 + hid;
            pack8 p;
            #pragma unroll
            for (int j = 0; j < 8; ++j) p.h[j] = (_Float16)(src[j] * sc);
            wf[e] = p.u;
        } else if (e < 2176) {
            // s-projection fragments (frags 32,33): B[k][0]=w_s[k] (UNSCALED)
            int t2 = e - 2048;
            int l = t2 & 63, kc = t2 >> 6;
            pack8 p;
            #pragma unroll
            for (int j = 0; j < 8; ++j) p.h[j] = (_Float16)0.0f;
            if ((l & 15) == 0) {
                #pragma unroll
                for (int j = 0; j < 8; ++j)
                    p.h[j] = (_Float16)w_s[kc * 32 + (l >> 4) * 8 + j];
            }
            wf[e] = p.u;
        }
    } else {
        // {w_x, bias} pairs, permuted + pre-scaled.
        // read idx = s + 16*hb + 64*gi  ->  gate 64*gi + 4*s + hb
        int s_ = tid & 15, hb = (tid >> 4) & 3, gi = tid >> 6;
        int gate = gi * 64 + 4 * s_ + hb;
        float sc = (gi == 2) ? SG : SI;
        floatx2 v; v.x = w_ih[gate] * sc; v.y = (b_ih[gate] + b_hh[gate]) * sc;
        ((floatx2*)(ws_f + OFF_WXB))[tid] = v;
    }
}

// ---------------- fully fused conv_in + LSTM + conv_out ----------------
// Block = 512 threads = 8 waves = ONE 16-pixel tile x ALL 8 groups.
// r9: common-denominator LSTM cell; 5 exp2 + 2 rcp /elem (weights pre-scaled).
// r10 POST-MORTEM: full 32-frag hoist (136 VGPR) + forced 4 waves/SIMD =
// 128-reg cap -> catastrophic scratch spill (FETCH 8.5MB->1.3GB). The per-SIMD
// VGPR pool is 2048: at 16 waves/CU the HARD budget is 128 regs. Frags stay
// in LDS.
// r11 (bounded hoists, ~100 regs total):
//  - wxb (16 floatx2 = 32 VGPR) + s-proj frags (8 VGPR) hoisted; t-invariant,
//    removes 18 LDS reads/thread/t that the asm clobber was forcing.
//  - h-writes packed to 4x ds_write_b64 (gate-column permutation in prep).
//  - epilogue reads w_out rows as floatx4 (no transpose; 128 b32 -> 32 b128).
// asm clobber STAYS: frag/x/h LDS reads must not be register-cached (r7).
// LDS = 79872 B <= 81920 -> 2 blocks/CU = 16 waves/CU; bounds (512,4) pins it.
__global__ __launch_bounds__(512, 4) void lstm_kernel(
    const float* __restrict__ hin,    // (B, 64, HW) original input h
    const float* __restrict__ ws_f,   // tables
    float* __restrict__ out,          // (B, 64, HW) final output
    const float* __restrict__ w_in,   // (64, 64)
    const float* __restrict__ b_in,   // (64,)
    const float* __restrict__ b_s_p,  // (1,)
    const float* __restrict__ b_out,  // (64,)
    const float* __restrict__ w_out) {// (64, 64) [o][c]
    __shared__ uint4 wfrag_lds[2176];                  // 34816 B
    __shared__ floatx2 wxb_lds[256];                   // 2048 B
    __shared__ __align__(16) float x_lds[1024];        // 4096 B: [g][t][px16]
    __shared__ __align__(16) _Float16 h_lds[9216];     // 18432 B: 8 waves x 16 x 72
    __shared__ __align__(16) float stile[1024];        // 4096 B: [c64][px16]; aliases hin staging
    __shared__ __align__(16) float wt_lds[4096];       // 16384 B: w_in, then w_out

    int tid = threadIdx.x;
    int ptile = blockIdx.x & 255;         // 256 tiles of 16 px
    int b     = blockIdx.x >> 8;
    int p0 = ptile * 16;

    int lane = tid & 63;
    int wv   = tid >> 6;                  // 0..7 == group g
    int g    = wv;
    int s    = lane & 15;                 // seq-local == pixel-local
    int q    = lane >> 4;

    // stage weight fragments (shared by all 8 waves)
    const uint4* wfg = (const uint4*)(ws_f + OFF_WFRAG);
    #pragma unroll
    for (int i = 0; i < 5; ++i) {
        int e = tid + 512 * i;
        if (e < 2176) wfrag_lds[e] = wfg[e];
    }
    if (tid < 256) wxb_lds[tid] = ((const floatx2*)(ws_f + OFF_WXB))[tid];
    // stage w_in (identity copy, [o][c] row-major) into wt_lds
    #pragma unroll
    for (int i = 0; i < 2; ++i)
        ((floatx4*)wt_lds)[tid + 512 * i] = ((const floatx4*)w_in)[tid + 512 * i];
    // stage hin tile (64 ch x 16 px) into stile (aliased)
    if (tid < 256) {
        int cc = tid >> 2, f4 = tid & 3;
        ((floatx4*)stile)[tid] = *(const floatx4*)&hin[(b * 64 + cc) * HW + p0 + f4 * 4];
    }
    __syncthreads();

    // ---- conv_in (per wave, own group): x[g][t][px] = sum_c w_in[g8+t][c]*hin[c][px] + b_in
    {
        floatx2 xacc; xacc.x = b_in[g * 8 + q]; xacc.y = b_in[g * 8 + q + 4];
        #pragma unroll 8
        for (int cc = 0; cc < 64; ++cc) {
            float hv = stile[cc * 16 + s];
            floatx2 w;
            w.x = wt_lds[(g * 8 + q) * 64 + cc];
            w.y = wt_lds[(g * 8 + q + 4) * 64 + cc];
            floatx2 h2; h2.x = hv; h2.y = hv;
            xacc = xacc + w * h2;
        }
        x_lds[g * 128 + q * 16 + s]       = xacc.x;
        x_lds[g * 128 + (q + 4) * 16 + s] = xacc.y;
    }
    // zero h state (4608 u32)
    #pragma unroll
    for (int i = 0; i < 9; ++i)
        ((unsigned*)h_lds)[tid + 512 * i] = 0u;
    __syncthreads();   // hin/w_in reads + x/h writes complete

    // stage w_out ([o][c], as-is) into wt_lds for the epilogue
    #pragma unroll
    for (int i = 0; i < 2; ++i)
        ((floatx4*)wt_lds)[tid + 512 * i] = ((const floatx4*)w_out)[tid + 512 * i];

    // ---- r11 bounded hoists: wxb (32 VGPR) + s-proj frags (8 VGPR).
    // t-invariant SSA values; the asm clobber below does not invalidate them.
    floatx2 wbr[16];
    #pragma unroll
    for (int nb = 0; nb < 16; ++nb) wbr[nb] = wxb_lds[s + 16 * nb];
    halfx8 sb0 = *(const halfx8*)&wfrag_lds[32 * 64 + lane];
    halfx8 sb1 = *(const halfx8*)&wfrag_lds[33 * 64 + lane];

    _Float16* hrow = h_lds + wv * 16 * 72;
    float bs = b_s_p[0];

    // c-state, stored PRE-SCALED by 2*log2(e)
    float c_st[4][4];
    #pragma unroll
    for (int hb = 0; hb < 4; ++hb)
        #pragma unroll
        for (int r = 0; r < 4; ++r) c_st[hb][r] = 0.0f;

    for (int t = 0; t < TT; ++t) {
        // Memory barrier: forbids caching LDS (frags/x/h) in registers across
        // iterations (r7: uncontrolled caching balloons regs). Named reg
        // hoists above survive it.
        asm volatile("" ::: "memory");

        halfx8 a0 = *(const halfx8*)(hrow + s * 72 + q * 8);        // k = 0..31
        halfx8 a1 = *(const halfx8*)(hrow + s * 72 + q * 8 + 32);   // k = 32..63

        // s_{t-1} = h_t @ w_s via MFMA (col 0 only); lanes s==0 hold seq q*4+r
        if (t > 0) {
            floatx4 sa = {0.f, 0.f, 0.f, 0.f};
            sa = __builtin_amdgcn_mfma_f32_16x16x32_f16(a0, sb0, sa, 0, 0, 0);
            sa = __builtin_amdgcn_mfma_f32_16x16x32_f16(a1, sb1, sa, 0, 0, 0);
            if (s == 0) {
                floatx4 o4 = {sa[0] + bs, sa[1] + bs, sa[2] + bs, sa[3] + bs};
                *(floatx4*)&stile[(g * 8 + (t - 1)) * 16 + q * 4] = o4;
            }
        }

        floatx4 xv = *(const floatx4*)&x_lds[g * 128 + t * 16 + q * 4];
        floatx2 xlo; xlo.x = xv[0]; xlo.y = xv[1];
        floatx2 xhi; xhi.x = xv[2]; xhi.y = xv[3];

        halfx4 hpack[4];   // per-row packed h (hb-contiguous thanks to r11 perm)

        #pragma unroll
        for (int hb = 0; hb < 4; ++hb) {
            floatx4 acc[4];
            #pragma unroll
            for (int gi = 0; gi < 4; ++gi) {
                int nb = hb + 4 * gi;
                floatx2 wb = wbr[nb];
                floatx2 lo = xlo * wb.x + wb.y;     // x*w_x + bias as C init (pk_fma)
                floatx2 hi = xhi * wb.x + wb.y;
                floatx4 a = {lo.x, lo.y, hi.x, hi.y};
                halfx8 b0 = *(const halfx8*)&wfrag_lds[(nb * 2 + 0) * 64 + lane];
                halfx8 b1 = *(const halfx8*)&wfrag_lds[(nb * 2 + 1) * 64 + lane];
                a = __builtin_amdgcn_mfma_f32_16x16x32_f16(a0, b0, a, 0, 0, 0);
                a = __builtin_amdgcn_mfma_f32_16x16x32_f16(a1, b1, a, 0, 0, 0);
                acc[gi] = a;
            }
            #pragma unroll
            for (int p = 0; p < 2; ++p) {
                int r0 = 2 * p;
                // accs are pre-scaled: Ei=e^-i, Ef=e^-f, Eo=e^-o, Eg=e^{2g}
                floatx2 Ei; Ei.x = fast_exp2(acc[0][r0]); Ei.y = fast_exp2(acc[0][r0 + 1]);
                floatx2 Ef; Ef.x = fast_exp2(acc[1][r0]); Ef.y = fast_exp2(acc[1][r0 + 1]);
                floatx2 Eg; Eg.x = fast_exp2(acc[2][r0]); Eg.y = fast_exp2(acc[2][r0 + 1]);
                floatx2 Eo; Eo.x = fast_exp2(acc[3][r0]); Eo.y = fast_exp2(acc[3][r0 + 1]);
                floatx2 Bf  = Ef + 1.0f;
                floatx2 Pig = (Ei + 1.0f) * (Eg + 1.0f);
                floatx2 cp; cp.x = c_st[hb][r0]; cp.y = c_st[hb][r0 + 1];
                // cs' = f*cs + 2log2e * i*g  ==  [cs*Pig + SG*(Eg-1)*Bf] / (Bf*Pig)
                floatx2 num = cp * Pig + (Eg * SG - SG) * Bf;   // fma: SG*(Eg-1) exact
                floatx2 cs  = num * rcpx2(Bf * Pig);
                c_st[hb][r0] = cs.x; c_st[hb][r0 + 1] = cs.y;
                // h = o*tanh(c) = (Ec-1) / ((1+Eo)(1+Ec)),  Ec = exp2(cs) = e^{2c}
                floatx2 Ec  = exp2x2(cs);
                floatx2 hn  = (Ec - 1.0f) * rcpx2((Eo + 1.0f) * (Ec + 1.0f));
                hpack[r0 + 0][hb] = (_Float16)hn.x;
                hpack[r0 + 1][hb] = (_Float16)hn.y;
            }
        }
        // state for t+1: 4x ds_write_b64, hid = 4s..4s+3 per row (r11 perm)
        {
            _Float16* wp = hrow + (q * 4) * 72 + 4 * s;
            *(halfx4*)(wp +   0) = hpack[0];
            *(halfx4*)(wp +  72) = hpack[1];
            *(halfx4*)(wp + 144) = hpack[2];
            *(halfx4*)(wp + 216) = hpack[3];
        }
    }
    // final s_7 from h_8
    {
        asm volatile("" ::: "memory");
        halfx8 a0 = *(const halfx8*)(hrow + s * 72 + q * 8);
        halfx8 a1 = *(const halfx8*)(hrow + s * 72 + q * 8 + 32);
        floatx4 sa = {0.f, 0.f, 0.f, 0.f};
        sa = __builtin_amdgcn_mfma_f32_16x16x32_f16(a0, sb0, sa, 0, 0, 0);
        sa = __builtin_amdgcn_mfma_f32_16x16x32_f16(a1, sb1, sa, 0, 0, 0);
        if (s == 0) {
            floatx4 o4 = {sa[0] + bs, sa[1] + bs, sa[2] + bs, sa[3] + bs};
            *(floatx4*)&stile[(g * 8 + 7) * 16 + q * 4] = o4;
        }
    }
    __syncthreads();   // stile (all 64 channels) + wt_lds (w_out) ready

    // ---- conv_out epilogue: out[b][o][p0+px] = sum_c w_out[o][c]*stile[c][px] + b_out[o]
    {
        int px = tid & 15;
        int oo = tid >> 4;                 // 0..31 -> outputs oo and oo+32
        floatx2 acc; acc.x = b_out[oo]; acc.y = b_out[oo + 32];
        #pragma unroll
        for (int c4 = 0; c4 < 16; ++c4) {
            floatx4 w0 = *(const floatx4*)&wt_lds[oo * 64 + c4 * 4];
            floatx4 w1 = *(const floatx4*)&wt_lds[(oo + 32) * 64 + c4 * 4];
            #pragma unroll
            for (int j = 0; j < 4; ++j) {
                float sv = stile[(c4 * 4 + j) * 16 + px];
                acc.x += w0[j] * sv;
                acc.y += w1[j] * sv;
            }
        }
        out[(b * 64 + oo) * HW + p0 + px]      = acc.x;
        out[(b * 64 + oo + 32) * HW + p0 + px] = acc.y;
    }
}

extern "C" void kernel_launch(void* const* d_in, const int* in_sizes, int n_in,
                              void* d_out, int out_size, void* d_ws, size_t ws_size,
                              hipStream_t stream) {
    const float* h     = (const float*)d_in[0];
    const float* w_in  = (const float*)d_in[1];
    const float* b_in  = (const float*)d_in[2];
    const float* w_ih  = (const float*)d_in[3];
    const float* w_hh  = (const float*)d_in[4];
    const float* b_ih  = (const float*)d_in[5];
    const float* b_hh  = (const float*)d_in[6];
    const float* w_s   = (const float*)d_in[7];
    const float* b_s   = (const float*)d_in[8];
    const float* w_out = (const float*)d_in[9];
    const float* b_out = (const float*)d_in[10];
    float* out = (float*)d_out;
    float* ws  = (float*)d_ws;

    prep_kernel<<<10, 256, 0, stream>>>(w_ih, w_hh, b_ih, b_hh, w_s, w_out, ws);
    // fully fused conv_in + LSTM + conv_out: hin -> out. 2048 blocks x 512 threads.
    lstm_kernel<<<2048, 512, 0, stream>>>(h, ws, out, w_in, b_in, b_s, b_out, w_out);
}

// Round 4
// 257.020 us; speedup vs baseline: 2.0250x; 1.8733x over previous
//
#include <hip/hip_runtime.h>
#include <hip/hip_bf16.h>

// ---------------- problem constants ----------------
#define HW    4096      // H*W
#define BB    8         // batch
#define TT    8         // time steps

// ws layout (in floats)
constexpr int OFF_WFRAG = 0;                   // 34 frags * 64 lanes * 16B = 8704 floats
constexpr int OFF_WXB   = 12800;               // 256 float2 = 512 floats {w_x, bias}

// gate pre-scales folded into w_hh / w_x / bias at prep time:
//   i,f,o rows: * -log2(e)   -> sigmoid(x) = rcp(exp2(acc)+1)
//   g rows:     * 2*log2(e)  -> tanh(x) = (exp2(acc)-1)/(exp2(acc)+1)
constexpr float SI = -1.44269504088896340736f; // -log2(e)
constexpr float SG =  2.88539008177792681472f; // 2*log2(e)

typedef _Float16 halfx8 __attribute__((ext_vector_type(8)));
typedef _Float16 halfx4 __attribute__((ext_vector_type(4)));
typedef float    floatx4 __attribute__((ext_vector_type(4)));
typedef float    floatx2 __attribute__((ext_vector_type(2)));

__device__ inline float fast_exp2(float x) {
#if __has_builtin(__builtin_amdgcn_exp2f)
    return __builtin_amdgcn_exp2f(x);
#else
    return __builtin_exp2f(x);
#endif
}
__device__ inline float fast_rcp(float x) {
#if __has_builtin(__builtin_amdgcn_rcpf)
    return __builtin_amdgcn_rcpf(x);
#else
    return 1.0f / x;
#endif
}
__device__ inline floatx2 exp2x2(floatx2 x) {
    floatx2 r; r.x = fast_exp2(x.x); r.y = fast_exp2(x.y); return r;
}
__device__ inline floatx2 rcpx2(floatx2 x) {
    floatx2 r; r.x = fast_rcp(x.x); r.y = fast_rcp(x.y); return r;
}

union pack8 { _Float16 h[8]; uint4 u; };

// ---------------- prep: repack weights into d_ws (10 blocks) ----------------
// r9: folds activation pre-scales (SI/SG) into the f16 B-fragments and the
// {w_x,bias} table so t-loop exp2 args come straight out of the MFMA accs.
// r11: gate-column PERMUTATION — frag column sc of block nb=(hb+4gi) holds
// orig gate row 64*gi + 4*sc + hb. Thread (s,hb) then produces hid = 4s+hb
// -> its 4 hb-values are CONTIGUOUS in h_lds -> one ds_write_b64 per row.
__global__ __launch_bounds__(256) void prep_kernel(
    const float* __restrict__ w_ih,  const float* __restrict__ w_hh,
    const float* __restrict__ b_ih,  const float* __restrict__ b_hh,
    const float* __restrict__ w_s,   const float* __restrict__ w_out,
    float* __restrict__ ws_f) {
    int tid = threadIdx.x;
    int bid = blockIdx.x;
    if (bid < 9) {
        int e = bid * 256 + tid;
        uint4* wf = (uint4*)(ws_f + OFF_WFRAG);
        if (e < 2048) {
            int l  = e & 63;
            int fi = e >> 6;
            int nb = fi >> 1, kc = fi & 1;
            int hb = nb & 3, gi = nb >> 2;
            int gate = gi * 64 + 4 * (l & 15) + hb;   // r11 permuted column
            int hid  = kc * 32 + (l >> 4) * 8;
            float sc = (gi == 2) ? SG : SI;
            const float* src = w_hh + gate * 64 + hid;
            pack8 p;
            #pragma unroll
            for (int j = 0; j < 8; ++j) p.h[j] = (_Float16)(src[j] * sc);
            wf[e] = p.u;
        } else if (e < 2176) {
            // s-projection fragments (frags 32,33): B[k][0]=w_s[k] (UNSCALED)
            int t2 = e - 2048;
            int l = t2 & 63, kc = t2 >> 6;
            pack8 p;
            #pragma unroll
            for (int j = 0; j < 8; ++j) p.h[j] = (_Float16)0.0f;
            if ((l & 15) == 0) {
                #pragma unroll
                for (int j = 0; j < 8; ++j)
                    p.h[j] = (_Float16)w_s[kc * 32 + (l >> 4) * 8 + j];
            }
            wf[e] = p.u;
        }
    } else {
        // {w_x, bias} pairs, permuted + pre-scaled.
        // read idx = s + 16*hb + 64*gi  ->  gate 64*gi + 4*s + hb
        int s_ = tid & 15, hb = (tid >> 4) & 3, gi = tid >> 6;
        int gate = gi * 64 + 4 * s_ + hb;
        float sc = (gi == 2) ? SG : SI;
        floatx2 v; v.x = w_ih[gate] * sc; v.y = (b_ih[gate] + b_hh[gate]) * sc;
        ((floatx2*)(ws_f + OFF_WXB))[tid] = v;
    }
}

// ---------------- fully fused conv_in + LSTM + conv_out ----------------
// Block = 512 threads = 8 waves = ONE 16-pixel tile x ALL 8 groups.
// r9: common-denominator LSTM cell; 5 exp2 + 2 rcp /elem (weights pre-scaled).
// r10/r11 POST-MORTEM: __launch_bounds__(512, 4) on THIS toolchain produces a
// 64-VGPR cap (observed twice: VGPR_Count=64 + 1.1-1.3 GB scratch FETCH).
// The "min waves per EU" formula (arg 4 -> 128 cap) does NOT hold here.
// r12 fix: plain __launch_bounds__(512). The backend derives the occupancy
// target from LDS (79872 B -> 2 blocks/CU -> 4 waves/SIMD -> 128-reg cap),
// which fits the ~100-reg working set of the r11 hoists without spill
// (r9 evidence: plain bound chose 52 regs, no spill).
// r11 hoists (kept): wxb (16 floatx2 = 32 VGPR) + s-proj frags (8 VGPR)
// hoisted to regs; h-writes packed to 4x ds_write_b64 (gate-col perm);
// epilogue reads w_out rows as floatx4 (no transpose).
// asm clobber STAYS: frag/x/h LDS reads must not be register-cached (r7).
// LDS = 79872 B <= 81920 -> 2 blocks/CU = 16 waves/CU.
__global__ __launch_bounds__(512) void lstm_kernel(
    const float* __restrict__ hin,    // (B, 64, HW) original input h
    const float* __restrict__ ws_f,   // tables
    float* __restrict__ out,          // (B, 64, HW) final output
    const float* __restrict__ w_in,   // (64, 64)
    const float* __restrict__ b_in,   // (64,)
    const float* __restrict__ b_s_p,  // (1,)
    const float* __restrict__ b_out,  // (64,)
    const float* __restrict__ w_out) {// (64, 64) [o][c]
    __shared__ uint4 wfrag_lds[2176];                  // 34816 B
    __shared__ floatx2 wxb_lds[256];                   // 2048 B
    __shared__ __align__(16) float x_lds[1024];        // 4096 B: [g][t][px16]
    __shared__ __align__(16) _Float16 h_lds[9216];     // 18432 B: 8 waves x 16 x 72
    __shared__ __align__(16) float stile[1024];        // 4096 B: [c64][px16]; aliases hin staging
    __shared__ __align__(16) float wt_lds[4096];       // 16384 B: w_in, then w_out

    int tid = threadIdx.x;
    int ptile = blockIdx.x & 255;         // 256 tiles of 16 px
    int b     = blockIdx.x >> 8;
    int p0 = ptile * 16;

    int lane = tid & 63;
    int wv   = tid >> 6;                  // 0..7 == group g
    int g    = wv;
    int s    = lane & 15;                 // seq-local == pixel-local
    int q    = lane >> 4;

    // stage weight fragments (shared by all 8 waves)
    const uint4* wfg = (const uint4*)(ws_f + OFF_WFRAG);
    #pragma unroll
    for (int i = 0; i < 5; ++i) {
        int e = tid + 512 * i;
        if (e < 2176) wfrag_lds[e] = wfg[e];
    }
    if (tid < 256) wxb_lds[tid] = ((const floatx2*)(ws_f + OFF_WXB))[tid];
    // stage w_in (identity copy, [o][c] row-major) into wt_lds
    #pragma unroll
    for (int i = 0; i < 2; ++i)
        ((floatx4*)wt_lds)[tid + 512 * i] = ((const floatx4*)w_in)[tid + 512 * i];
    // stage hin tile (64 ch x 16 px) into stile (aliased)
    if (tid < 256) {
        int cc = tid >> 2, f4 = tid & 3;
        ((floatx4*)stile)[tid] = *(const floatx4*)&hin[(b * 64 + cc) * HW + p0 + f4 * 4];
    }
    __syncthreads();

    // ---- conv_in (per wave, own group): x[g][t][px] = sum_c w_in[g8+t][c]*hin[c][px] + b_in
    {
        floatx2 xacc; xacc.x = b_in[g * 8 + q]; xacc.y = b_in[g * 8 + q + 4];
        #pragma unroll 8
        for (int cc = 0; cc < 64; ++cc) {
            float hv = stile[cc * 16 + s];
            floatx2 w;
            w.x = wt_lds[(g * 8 + q) * 64 + cc];
            w.y = wt_lds[(g * 8 + q + 4) * 64 + cc];
            floatx2 h2; h2.x = hv; h2.y = hv;
            xacc = xacc + w * h2;
        }
        x_lds[g * 128 + q * 16 + s]       = xacc.x;
        x_lds[g * 128 + (q + 4) * 16 + s] = xacc.y;
    }
    // zero h state (4608 u32)
    #pragma unroll
    for (int i = 0; i < 9; ++i)
        ((unsigned*)h_lds)[tid + 512 * i] = 0u;
    __syncthreads();   // hin/w_in reads + x/h writes complete

    // stage w_out ([o][c], as-is) into wt_lds for the epilogue
    #pragma unroll
    for (int i = 0; i < 2; ++i)
        ((floatx4*)wt_lds)[tid + 512 * i] = ((const floatx4*)w_out)[tid + 512 * i];

    // ---- r11 bounded hoists: wxb (32 VGPR) + s-proj frags (8 VGPR).
    // t-invariant SSA values; the asm clobber below does not invalidate them.
    floatx2 wbr[16];
    #pragma unroll
    for (int nb = 0; nb < 16; ++nb) wbr[nb] = wxb_lds[s + 16 * nb];
    halfx8 sb0 = *(const halfx8*)&wfrag_lds[32 * 64 + lane];
    halfx8 sb1 = *(const halfx8*)&wfrag_lds[33 * 64 + lane];

    _Float16* hrow = h_lds + wv * 16 * 72;
    float bs = b_s_p[0];

    // c-state, stored PRE-SCALED by 2*log2(e)
    float c_st[4][4];
    #pragma unroll
    for (int hb = 0; hb < 4; ++hb)
        #pragma unroll
        for (int r = 0; r < 4; ++r) c_st[hb][r] = 0.0f;

    for (int t = 0; t < TT; ++t) {
        // Memory barrier: forbids caching LDS (frags/x/h) in registers across
        // iterations (r7: uncontrolled caching balloons regs). Named reg
        // hoists above survive it.
        asm volatile("" ::: "memory");

        halfx8 a0 = *(const halfx8*)(hrow + s * 72 + q * 8);        // k = 0..31
        halfx8 a1 = *(const halfx8*)(hrow + s * 72 + q * 8 + 32);   // k = 32..63

        // s_{t-1} = h_t @ w_s via MFMA (col 0 only); lanes s==0 hold seq q*4+r
        if (t > 0) {
            floatx4 sa = {0.f, 0.f, 0.f, 0.f};
            sa = __builtin_amdgcn_mfma_f32_16x16x32_f16(a0, sb0, sa, 0, 0, 0);
            sa = __builtin_amdgcn_mfma_f32_16x16x32_f16(a1, sb1, sa, 0, 0, 0);
            if (s == 0) {
                floatx4 o4 = {sa[0] + bs, sa[1] + bs, sa[2] + bs, sa[3] + bs};
                *(floatx4*)&stile[(g * 8 + (t - 1)) * 16 + q * 4] = o4;
            }
        }

        floatx4 xv = *(const floatx4*)&x_lds[g * 128 + t * 16 + q * 4];
        floatx2 xlo; xlo.x = xv[0]; xlo.y = xv[1];
        floatx2 xhi; xhi.x = xv[2]; xhi.y = xv[3];

        halfx4 hpack[4];   // per-row packed h (hb-contiguous thanks to r11 perm)

        #pragma unroll
        for (int hb = 0; hb < 4; ++hb) {
            floatx4 acc[4];
            #pragma unroll
            for (int gi = 0; gi < 4; ++gi) {
                int nb = hb + 4 * gi;
                floatx2 wb = wbr[nb];
                floatx2 lo = xlo * wb.x + wb.y;     // x*w_x + bias as C init (pk_fma)
                floatx2 hi = xhi * wb.x + wb.y;
                floatx4 a = {lo.x, lo.y, hi.x, hi.y};
                halfx8 b0 = *(const halfx8*)&wfrag_lds[(nb * 2 + 0) * 64 + lane];
                halfx8 b1 = *(const halfx8*)&wfrag_lds[(nb * 2 + 1) * 64 + lane];
                a = __builtin_amdgcn_mfma_f32_16x16x32_f16(a0, b0, a, 0, 0, 0);
                a = __builtin_amdgcn_mfma_f32_16x16x32_f16(a1, b1, a, 0, 0, 0);
                acc[gi] = a;
            }
            #pragma unroll
            for (int p = 0; p < 2; ++p) {
                int r0 = 2 * p;
                // accs are pre-scaled: Ei=e^-i, Ef=e^-f, Eo=e^-o, Eg=e^{2g}
                floatx2 Ei; Ei.x = fast_exp2(acc[0][r0]); Ei.y = fast_exp2(acc[0][r0 + 1]);
                floatx2 Ef; Ef.x = fast_exp2(acc[1][r0]); Ef.y = fast_exp2(acc[1][r0 + 1]);
                floatx2 Eg; Eg.x = fast_exp2(acc[2][r0]); Eg.y = fast_exp2(acc[2][r0 + 1]);
                floatx2 Eo; Eo.x = fast_exp2(acc[3][r0]); Eo.y = fast_exp2(acc[3][r0 + 1]);
                floatx2 Bf  = Ef + 1.0f;
                floatx2 Pig = (Ei + 1.0f) * (Eg + 1.0f);
                floatx2 cp; cp.x = c_st[hb][r0]; cp.y = c_st[hb][r0 + 1];
                // cs' = f*cs + 2log2e * i*g  ==  [cs*Pig + SG*(Eg-1)*Bf] / (Bf*Pig)
                floatx2 num = cp * Pig + (Eg * SG - SG) * Bf;   // fma: SG*(Eg-1) exact
                floatx2 cs  = num * rcpx2(Bf * Pig);
                c_st[hb][r0] = cs.x; c_st[hb][r0 + 1] = cs.y;
                // h = o*tanh(c) = (Ec-1) / ((1+Eo)(1+Ec)),  Ec = exp2(cs) = e^{2c}
                floatx2 Ec  = exp2x2(cs);
                floatx2 hn  = (Ec - 1.0f) * rcpx2((Eo + 1.0f) * (Ec + 1.0f));
                hpack[r0 + 0][hb] = (_Float16)hn.x;
                hpack[r0 + 1][hb] = (_Float16)hn.y;
            }
        }
        // state for t+1: 4x ds_write_b64, hid = 4s..4s+3 per row (r11 perm)
        {
            _Float16* wp = hrow + (q * 4) * 72 + 4 * s;
            *(halfx4*)(wp +   0) = hpack[0];
            *(halfx4*)(wp +  72) = hpack[1];
            *(halfx4*)(wp + 144) = hpack[2];
            *(halfx4*)(wp + 216) = hpack[3];
        }
    }
    // final s_7 from h_8
    {
        asm volatile("" ::: "memory");
        halfx8 a0 = *(const halfx8*)(hrow + s * 72 + q * 8);
        halfx8 a1 = *(const halfx8*)(hrow + s * 72 + q * 8 + 32);
        floatx4 sa = {0.f, 0.f, 0.f, 0.f};
        sa = __builtin_amdgcn_mfma_f32_16x16x32_f16(a0, sb0, sa, 0, 0, 0);
        sa = __builtin_amdgcn_mfma_f32_16x16x32_f16(a1, sb1, sa, 0, 0, 0);
        if (s == 0) {
            floatx4 o4 = {sa[0] + bs, sa[1] + bs, sa[2] + bs, sa[3] + bs};
            *(floatx4*)&stile[(g * 8 + 7) * 16 + q * 4] = o4;
        }
    }
    __syncthreads();   // stile (all 64 channels) + wt_lds (w_out) ready

    // ---- conv_out epilogue: out[b][o][p0+px] = sum_c w_out[o][c]*stile[c][px] + b_out[o]
    {
        int px = tid & 15;
        int oo = tid >> 4;                 // 0..31 -> outputs oo and oo+32
        floatx2 acc; acc.x = b_out[oo]; acc.y = b_out[oo + 32];
        #pragma unroll
        for (int c4 = 0; c4 < 16; ++c4) {
            floatx4 w0 = *(const floatx4*)&wt_lds[oo * 64 + c4 * 4];
            floatx4 w1 = *(const floatx4*)&wt_lds[(oo + 32) * 64 + c4 * 4];
            #pragma unroll
            for (int j = 0; j < 4; ++j) {
                float sv = stile[(c4 * 4 + j) * 16 + px];
                acc.x += w0[j] * sv;
                acc.y += w1[j] * sv;
            }
        }
        out[(b * 64 + oo) * HW + p0 + px]      = acc.x;
        out[(b * 64 + oo + 32) * HW + p0 + px] = acc.y;
    }
}

extern "C" void kernel_launch(void* const* d_in, const int* in_sizes, int n_in,
                              void* d_out, int out_size, void* d_ws, size_t ws_size,
                              hipStream_t stream) {
    const float* h     = (const float*)d_in[0];
    const float* w_in  = (const float*)d_in[1];
    const float* b_in  = (const float*)d_in[2];
    const float* w_ih  = (const float*)d_in[3];
    const float* w_hh  = (const float*)d_in[4];
    const float* b_ih  = (const float*)d_in[5];
    const float* b_hh  = (const float*)d_in[6];
    const float* w_s   = (const float*)d_in[7];
    const float* b_s   = (const float*)d_in[8];
    const float* w_out = (const float*)d_in[9];
    const float* b_out = (const float*)d_in[10];
    float* out = (float*)d_out;
    float* ws  = (float*)d_ws;

    prep_kernel<<<10, 256, 0, stream>>>(w_ih, w_hh, b_ih, b_hh, w_s, w_out, ws);
    // fully fused conv_in + LSTM + conv_out: hin -> out. 2048 blocks x 512 threads.
    lstm_kernel<<<2048, 512, 0, stream>>>(h, ws, out, w_in, b_in, b_s, b_out, w_out);
}

// Round 5
// 223.223 us; speedup vs baseline: 2.3316x; 1.1514x over previous
//
#include <hip/hip_runtime.h>
#include <hip/hip_bf16.h>

// ---------------- problem constants ----------------
#define HW    4096      // H*W
#define BB    8         // batch
#define TT    8         // time steps

// ws layout (in floats)
constexpr int OFF_WFRAG = 0;                   // 34 frags * 64 lanes * 16B = 8704 floats
constexpr int OFF_WXB   = 12800;               // 256 float2 = 512 floats {w_x, bias}

// gate pre-scales folded into w_hh / w_x / bias at prep time:
//   i,f,o rows: * -log2(e)   -> sigmoid(x) = rcp(exp2(acc)+1)
//   g rows:     * 2*log2(e)  -> tanh(x) = (exp2(acc)-1)/(exp2(acc)+1)
constexpr float SI = -1.44269504088896340736f; // -log2(e)
constexpr float SG =  2.88539008177792681472f; // 2*log2(e)

typedef _Float16 halfx8 __attribute__((ext_vector_type(8)));
typedef _Float16 halfx4 __attribute__((ext_vector_type(4)));
typedef float    floatx4 __attribute__((ext_vector_type(4)));
typedef float    floatx2 __attribute__((ext_vector_type(2)));

__device__ inline float fast_exp2(float x) {
#if __has_builtin(__builtin_amdgcn_exp2f)
    return __builtin_amdgcn_exp2f(x);
#else
    return __builtin_exp2f(x);
#endif
}
__device__ inline float fast_rcp(float x) {
#if __has_builtin(__builtin_amdgcn_rcpf)
    return __builtin_amdgcn_rcpf(x);
#else
    return 1.0f / x;
#endif
}
__device__ inline floatx2 exp2x2(floatx2 x) {
    floatx2 r; r.x = fast_exp2(x.x); r.y = fast_exp2(x.y); return r;
}
__device__ inline floatx2 rcpx2(floatx2 x) {
    floatx2 r; r.x = fast_rcp(x.x); r.y = fast_rcp(x.y); return r;
}

union pack8 { _Float16 h[8]; uint4 u; };

// ---------------- prep: repack weights into d_ws (10 blocks) ----------------
// r9: folds activation pre-scales (SI/SG) into the f16 B-fragments and the
// {w_x,bias} table so t-loop exp2 args come straight out of the MFMA accs.
// r11: gate-column PERMUTATION — frag column sc of block nb=(hb+4gi) holds
// orig gate row 64*gi + 4*sc + hb. Thread (s,hb) then produces hid = 4s+hb
// -> its 4 hb-values are CONTIGUOUS in h_lds -> one ds_write_b64 per row.
// (k-index/storage hid = original hid, so w_s and A-reads are unaffected.)
__global__ __launch_bounds__(256) void prep_kernel(
    const float* __restrict__ w_ih,  const float* __restrict__ w_hh,
    const float* __restrict__ b_ih,  const float* __restrict__ b_hh,
    const float* __restrict__ w_s,   const float* __restrict__ w_out,
    float* __restrict__ ws_f) {
    int tid = threadIdx.x;
    int bid = blockIdx.x;
    if (bid < 9) {
        int e = bid * 256 + tid;
        uint4* wf = (uint4*)(ws_f + OFF_WFRAG);
        if (e < 2048) {
            int l  = e & 63;
            int fi = e >> 6;
            int nb = fi >> 1, kc = fi & 1;
            int hb = nb & 3, gi = nb >> 2;
            int gate = gi * 64 + 4 * (l & 15) + hb;   // r11 permuted column
            int hid  = kc * 32 + (l >> 4) * 8;
            float sc = (gi == 2) ? SG : SI;
            const float* src = w_hh + gate * 64 + hid;
            pack8 p;
            #pragma unroll
            for (int j = 0; j < 8; ++j) p.h[j] = (_Float16)(src[j] * sc);
            wf[e] = p.u;
        } else if (e < 2176) {
            // s-projection fragments (frags 32,33): B[k][0]=w_s[k] (UNSCALED)
            int t2 = e - 2048;
            int l = t2 & 63, kc = t2 >> 6;
            pack8 p;
            #pragma unroll
            for (int j = 0; j < 8; ++j) p.h[j] = (_Float16)0.0f;
            if ((l & 15) == 0) {
                #pragma unroll
                for (int j = 0; j < 8; ++j)
                    p.h[j] = (_Float16)w_s[kc * 32 + (l >> 4) * 8 + j];
            }
            wf[e] = p.u;
        }
    } else {
        // {w_x, bias} pairs, permuted + pre-scaled.
        // read idx = s + 16*hb + 64*gi  ->  gate 64*gi + 4*s + hb
        int s_ = tid & 15, hb = (tid >> 4) & 3, gi = tid >> 6;
        int gate = gi * 64 + 4 * s_ + hb;
        float sc = (gi == 2) ? SG : SI;
        floatx2 v; v.x = w_ih[gate] * sc; v.y = (b_ih[gate] + b_hh[gate]) * sc;
        ((floatx2*)(ws_f + OFF_WXB))[tid] = v;
    }
}

// ---------------- fully fused conv_in + LSTM + conv_out ----------------
// Block = 512 threads = 8 waves = ONE 16-pixel tile x ALL 8 groups.
// r9: common-denominator LSTM cell; 5 exp2 + 2 rcp /elem (weights pre-scaled).
// r12 POST-MORTEM: the OCCUPANCY CLIFF for an 8-wave block is in VGPR
// (64, 108] on this HW (VGPR 52/64 -> 2 blocks/CU, occ ~41-45%; VGPR 108 ->
// 1 block/CU, occ 22%, dur +15%). Likely the MFMA AGPRs count into the
// unified budget on top of reported VGPR_Count. The r11 wxb/sb hoists
// (+40 regs) cost half the latency hiding -> net loss.
// r13: REVERT the hoists (wxb + s-frags read from LDS per-t, r9 pattern),
// KEEP the cheap wins: b64-packed h-writes (gate-col perm, -12 DS instrs/t),
// floatx4 w_out epilogue (no transpose, -96 DS instrs). Target VGPR <= 64.
// asm clobber STAYS: frag/x/h LDS reads must not be register-cached (r7).
// Plain __launch_bounds__(512): the (512,4) form caps at 64 regs + spills
// (r10/r11); plain lets the backend pick. LDS = 79872 B -> 2 blocks/CU.
__global__ __launch_bounds__(512) void lstm_kernel(
    const float* __restrict__ hin,    // (B, 64, HW) original input h
    const float* __restrict__ ws_f,   // tables
    float* __restrict__ out,          // (B, 64, HW) final output
    const float* __restrict__ w_in,   // (64, 64)
    const float* __restrict__ b_in,   // (64,)
    const float* __restrict__ b_s_p,  // (1,)
    const float* __restrict__ b_out,  // (64,)
    const float* __restrict__ w_out) {// (64, 64) [o][c]
    __shared__ uint4 wfrag_lds[2176];                  // 34816 B
    __shared__ floatx2 wxb_lds[256];                   // 2048 B
    __shared__ __align__(16) float x_lds[1024];        // 4096 B: [g][t][px16]
    __shared__ __align__(16) _Float16 h_lds[9216];     // 18432 B: 8 waves x 16 x 72
    __shared__ __align__(16) float stile[1024];        // 4096 B: [c64][px16]; aliases hin staging
    __shared__ __align__(16) float wt_lds[4096];       // 16384 B: w_in, then w_out

    int tid = threadIdx.x;
    int ptile = blockIdx.x & 255;         // 256 tiles of 16 px
    int b     = blockIdx.x >> 8;
    int p0 = ptile * 16;

    int lane = tid & 63;
    int wv   = tid >> 6;                  // 0..7 == group g
    int g    = wv;
    int s    = lane & 15;                 // seq-local == pixel-local
    int q    = lane >> 4;

    // stage weight fragments (shared by all 8 waves)
    const uint4* wfg = (const uint4*)(ws_f + OFF_WFRAG);
    #pragma unroll
    for (int i = 0; i < 5; ++i) {
        int e = tid + 512 * i;
        if (e < 2176) wfrag_lds[e] = wfg[e];
    }
    if (tid < 256) wxb_lds[tid] = ((const floatx2*)(ws_f + OFF_WXB))[tid];
    // stage w_in (identity copy, [o][c] row-major) into wt_lds
    #pragma unroll
    for (int i = 0; i < 2; ++i)
        ((floatx4*)wt_lds)[tid + 512 * i] = ((const floatx4*)w_in)[tid + 512 * i];
    // stage hin tile (64 ch x 16 px) into stile (aliased)
    if (tid < 256) {
        int cc = tid >> 2, f4 = tid & 3;
        ((floatx4*)stile)[tid] = *(const floatx4*)&hin[(b * 64 + cc) * HW + p0 + f4 * 4];
    }
    __syncthreads();

    // ---- conv_in (per wave, own group): x[g][t][px] = sum_c w_in[g8+t][c]*hin[c][px] + b_in
    {
        floatx2 xacc; xacc.x = b_in[g * 8 + q]; xacc.y = b_in[g * 8 + q + 4];
        #pragma unroll 8
        for (int cc = 0; cc < 64; ++cc) {
            float hv = stile[cc * 16 + s];
            floatx2 w;
            w.x = wt_lds[(g * 8 + q) * 64 + cc];
            w.y = wt_lds[(g * 8 + q + 4) * 64 + cc];
            floatx2 h2; h2.x = hv; h2.y = hv;
            xacc = xacc + w * h2;
        }
        x_lds[g * 128 + q * 16 + s]       = xacc.x;
        x_lds[g * 128 + (q + 4) * 16 + s] = xacc.y;
    }
    // zero h state (4608 u32)
    #pragma unroll
    for (int i = 0; i < 9; ++i)
        ((unsigned*)h_lds)[tid + 512 * i] = 0u;
    __syncthreads();   // hin/w_in reads + x/h writes complete

    // stage w_out ([o][c], as-is) into wt_lds for the epilogue
    #pragma unroll
    for (int i = 0; i < 2; ++i)
        ((floatx4*)wt_lds)[tid + 512 * i] = ((const floatx4*)w_out)[tid + 512 * i];

    _Float16* hrow = h_lds + wv * 16 * 72;
    float bs = b_s_p[0];

    // c-state, stored PRE-SCALED by 2*log2(e)
    float c_st[4][4];
    #pragma unroll
    for (int hb = 0; hb < 4; ++hb)
        #pragma unroll
        for (int r = 0; r < 4; ++r) c_st[hb][r] = 0.0f;

    for (int t = 0; t < TT; ++t) {
        // Memory barrier: forbids caching LDS (frags/wxb/x/h) in registers
        // across iterations (r7/r12: caching balloons regs past the
        // occupancy cliff; LDS re-reads are cheaper than lost occupancy).
        asm volatile("" ::: "memory");

        halfx8 a0 = *(const halfx8*)(hrow + s * 72 + q * 8);        // k = 0..31
        halfx8 a1 = *(const halfx8*)(hrow + s * 72 + q * 8 + 32);   // k = 32..63

        // s_{t-1} = h_t @ w_s via MFMA (col 0 only); lanes s==0 hold seq q*4+r
        if (t > 0) {
            halfx8 sb0 = *(const halfx8*)&wfrag_lds[32 * 64 + lane];
            halfx8 sb1 = *(const halfx8*)&wfrag_lds[33 * 64 + lane];
            floatx4 sa = {0.f, 0.f, 0.f, 0.f};
            sa = __builtin_amdgcn_mfma_f32_16x16x32_f16(a0, sb0, sa, 0, 0, 0);
            sa = __builtin_amdgcn_mfma_f32_16x16x32_f16(a1, sb1, sa, 0, 0, 0);
            if (s == 0) {
                floatx4 o4 = {sa[0] + bs, sa[1] + bs, sa[2] + bs, sa[3] + bs};
                *(floatx4*)&stile[(g * 8 + (t - 1)) * 16 + q * 4] = o4;
            }
        }

        floatx4 xv = *(const floatx4*)&x_lds[g * 128 + t * 16 + q * 4];
        floatx2 xlo; xlo.x = xv[0]; xlo.y = xv[1];
        floatx2 xhi; xhi.x = xv[2]; xhi.y = xv[3];

        halfx4 hpack[4];   // per-row packed h (hb-contiguous thanks to r11 perm)

        #pragma unroll
        for (int hb = 0; hb < 4; ++hb) {
            floatx4 acc[4];
            #pragma unroll
            for (int gi = 0; gi < 4; ++gi) {
                int nb = hb + 4 * gi;
                floatx2 wb = wxb_lds[s + 16 * nb];
                floatx2 lo = xlo * wb.x + wb.y;     // x*w_x + bias as C init (pk_fma)
                floatx2 hi = xhi * wb.x + wb.y;
                floatx4 a = {lo.x, lo.y, hi.x, hi.y};
                halfx8 b0 = *(const halfx8*)&wfrag_lds[(nb * 2 + 0) * 64 + lane];
                halfx8 b1 = *(const halfx8*)&wfrag_lds[(nb * 2 + 1) * 64 + lane];
                a = __builtin_amdgcn_mfma_f32_16x16x32_f16(a0, b0, a, 0, 0, 0);
                a = __builtin_amdgcn_mfma_f32_16x16x32_f16(a1, b1, a, 0, 0, 0);
                acc[gi] = a;
            }
            #pragma unroll
            for (int p = 0; p < 2; ++p) {
                int r0 = 2 * p;
                // accs are pre-scaled: Ei=e^-i, Ef=e^-f, Eo=e^-o, Eg=e^{2g}
                floatx2 Ei; Ei.x = fast_exp2(acc[0][r0]); Ei.y = fast_exp2(acc[0][r0 + 1]);
                floatx2 Ef; Ef.x = fast_exp2(acc[1][r0]); Ef.y = fast_exp2(acc[1][r0 + 1]);
                floatx2 Eg; Eg.x = fast_exp2(acc[2][r0]); Eg.y = fast_exp2(acc[2][r0 + 1]);
                floatx2 Eo; Eo.x = fast_exp2(acc[3][r0]); Eo.y = fast_exp2(acc[3][r0 + 1]);
                floatx2 Bf  = Ef + 1.0f;
                floatx2 Pig = (Ei + 1.0f) * (Eg + 1.0f);
                floatx2 cp; cp.x = c_st[hb][r0]; cp.y = c_st[hb][r0 + 1];
                // cs' = f*cs + 2log2e * i*g  ==  [cs*Pig + SG*(Eg-1)*Bf] / (Bf*Pig)
                floatx2 num = cp * Pig + (Eg * SG - SG) * Bf;   // fma: SG*(Eg-1) exact
                floatx2 cs  = num * rcpx2(Bf * Pig);
                c_st[hb][r0] = cs.x; c_st[hb][r0 + 1] = cs.y;
                // h = o*tanh(c) = (Ec-1) / ((1+Eo)(1+Ec)),  Ec = exp2(cs) = e^{2c}
                floatx2 Ec  = exp2x2(cs);
                floatx2 hn  = (Ec - 1.0f) * rcpx2((Eo + 1.0f) * (Ec + 1.0f));
                hpack[r0 + 0][hb] = (_Float16)hn.x;
                hpack[r0 + 1][hb] = (_Float16)hn.y;
            }
        }
        // state for t+1: 4x ds_write_b64, hid = 4s..4s+3 per row (r11 perm)
        {
            _Float16* wp = hrow + (q * 4) * 72 + 4 * s;
            *(halfx4*)(wp +   0) = hpack[0];
            *(halfx4*)(wp +  72) = hpack[1];
            *(halfx4*)(wp + 144) = hpack[2];
            *(halfx4*)(wp + 216) = hpack[3];
        }
    }
    // final s_7 from h_8
    {
        asm volatile("" ::: "memory");
        halfx8 a0 = *(const halfx8*)(hrow + s * 72 + q * 8);
        halfx8 a1 = *(const halfx8*)(hrow + s * 72 + q * 8 + 32);
        halfx8 sb0 = *(const halfx8*)&wfrag_lds[32 * 64 + lane];
        halfx8 sb1 = *(const halfx8*)&wfrag_lds[33 * 64 + lane];
        floatx4 sa = {0.f, 0.f, 0.f, 0.f};
        sa = __builtin_amdgcn_mfma_f32_16x16x32_f16(a0, sb0, sa, 0, 0, 0);
        sa = __builtin_amdgcn_mfma_f32_16x16x32_f16(a1, sb1, sa, 0, 0, 0);
        if (s == 0) {
            floatx4 o4 = {sa[0] + bs, sa[1] + bs, sa[2] + bs, sa[3] + bs};
            *(floatx4*)&stile[(g * 8 + 7) * 16 + q * 4] = o4;
        }
    }
    __syncthreads();   // stile (all 64 channels) + wt_lds (w_out) ready

    // ---- conv_out epilogue: out[b][o][p0+px] = sum_c w_out[o][c]*stile[c][px] + b_out[o]
    {
        int px = tid & 15;
        int oo = tid >> 4;                 // 0..31 -> outputs oo and oo+32
        floatx2 acc; acc.x = b_out[oo]; acc.y = b_out[oo + 32];
        #pragma unroll
        for (int c4 = 0; c4 < 16; ++c4) {
            floatx4 w0 = *(const floatx4*)&wt_lds[oo * 64 + c4 * 4];
            floatx4 w1 = *(const floatx4*)&wt_lds[(oo + 32) * 64 + c4 * 4];
            #pragma unroll
            for (int j = 0; j < 4; ++j) {
                float sv = stile[(c4 * 4 + j) * 16 + px];
                acc.x += w0[j] * sv;
                acc.y += w1[j] * sv;
            }
        }
        out[(b * 64 + oo) * HW + p0 + px]      = acc.x;
        out[(b * 64 + oo + 32) * HW + p0 + px] = acc.y;
    }
}

extern "C" void kernel_launch(void* const* d_in, const int* in_sizes, int n_in,
                              void* d_out, int out_size, void* d_ws, size_t ws_size,
                              hipStream_t stream) {
    const float* h     = (const float*)d_in[0];
    const float* w_in  = (const float*)d_in[1];
    const float* b_in  = (const float*)d_in[2];
    const float* w_ih  = (const float*)d_in[3];
    const float* w_hh  = (const float*)d_in[4];
    const float* b_ih  = (const float*)d_in[5];
    const float* b_hh  = (const float*)d_in[6];
    const float* w_s   = (const float*)d_in[7];
    const float* b_s   = (const float*)d_in[8];
    const float* w_out = (const float*)d_in[9];
    const float* b_out = (const float*)d_in[10];
    float* out = (float*)d_out;
    float* ws  = (float*)d_ws;

    prep_kernel<<<10, 256, 0, stream>>>(w_ih, w_hh, b_ih, b_hh, w_s, w_out, ws);
    // fully fused conv_in + LSTM + conv_out: hin -> out. 2048 blocks x 512 threads.
    lstm_kernel<<<2048, 512, 0, stream>>>(h, ws, out, w_in, b_in, b_s, b_out, w_out);
}